// Round 14
// baseline (287.579 us; speedup 1.0000x reference)
//
#include <hip/hip_runtime.h>
#include <hip/hip_bf16.h>
#include <cstdint>
#include <cstddef>

// MHA forward: out = (softmax(QK^T/8) V) Wo + bo, plus p_attn (fp32).
// R14 = R11 (best, 275.8us) + merged prep launch (conv3+tconvA in one kernel)
//     + s_setprio(1) around attn PV MFMA loop (T5; wave-specialized structure).

#define H_ 16
#define DK_ 64
#define DM_ 1024
#define WD_ 768
#define B_ 8
#define S_ 1024

typedef float f32x4 __attribute__((ext_vector_type(4)));
typedef __bf16 bf16x8 __attribute__((ext_vector_type(8)));
typedef short s16x8 __attribute__((ext_vector_type(8)));

__device__ __forceinline__ unsigned short f2bf(float x) {
  unsigned int u = __builtin_bit_cast(unsigned int, x);
  u += 0x7FFFu + ((u >> 16) & 1u);  // RNE
  return (unsigned short)(u >> 16);
}

__device__ __forceinline__ float bf2f(unsigned short b) {
  return __builtin_bit_cast(float, (unsigned int)b << 16);
}

__device__ __forceinline__ f32x4 mfma16(bf16x8 a, bf16x8 b, f32x4 c) {
  return __builtin_amdgcn_mfma_f32_16x16x32_bf16(a, b, c, 0, 0, 0);
}

__device__ __forceinline__ bf16x8 ld_bf8(const unsigned short* p) {
  return *reinterpret_cast<const bf16x8*>(p);
}

__device__ __forceinline__ void nt_store_f4(float* p, f32x4 v) {
  __builtin_nontemporal_store(v, reinterpret_cast<f32x4*>(p));
}

// bijective XCD swizzle (count % 8 == 0)
__device__ __forceinline__ int xcd_swz(int wg, int n) {
  int q = n >> 3;
  return (wg & 7) * q + (wg >> 3);
}

#define GLOAD_LDS16(g, l)                                            \
  __builtin_amdgcn_global_load_lds(                                  \
      (const __attribute__((address_space(1))) void*)(g),            \
      (__attribute__((address_space(3))) void*)(l), 16, 0, 0)

// swizzled LDS fragment read: row stride 128B, cb ^= (row&7)<<4
__device__ __forceinline__ bf16x8 lds_frag(const unsigned short* base, int row, int cb) {
  return *reinterpret_cast<const bf16x8*>(
      reinterpret_cast<const char*>(base) + row * 128 + (cb ^ ((row & 7) << 4)));
}

// ---------------- prep: activations conv (y=0..2) + weight transposes (y=3..6) ----------------
__global__ void k_prep(const float* __restrict__ q, const float* __restrict__ k,
                       const float* __restrict__ v, const float* __restrict__ Wq,
                       const float* __restrict__ Wk, const float* __restrict__ Wv,
                       const float* __restrict__ Wo, unsigned short* __restrict__ qo,
                       unsigned short* __restrict__ ko, unsigned short* __restrict__ vo,
                       unsigned short* __restrict__ Wqt, unsigned short* __restrict__ Wkt,
                       unsigned short* __restrict__ Wvt, unsigned short* __restrict__ Wot,
                       int n) {
  const int y = blockIdx.y;
  if (y < 3) {
    const float* in = y == 0 ? q : y == 1 ? k : v;
    unsigned short* out = y == 0 ? qo : y == 1 ? ko : vo;
    int i0 = (blockIdx.x * blockDim.x + threadIdx.x) * 8;
    int stride = gridDim.x * blockDim.x * 8;
    for (int i = i0; i < n; i += stride) {
      float4 a = *reinterpret_cast<const float4*>(in + i);
      float4 b = *reinterpret_cast<const float4*>(in + i + 4);
      s16x8 o;
      o[0] = (short)f2bf(a.x); o[1] = (short)f2bf(a.y);
      o[2] = (short)f2bf(a.z); o[3] = (short)f2bf(a.w);
      o[4] = (short)f2bf(b.x); o[5] = (short)f2bf(b.y);
      o[6] = (short)f2bf(b.z); o[7] = (short)f2bf(b.w);
      *reinterpret_cast<s16x8*>(out + i) = o;
    }
  } else {
    __shared__ float tt[32][33];
    const int z = y - 3;
    const float* W = z == 0 ? Wq : z == 1 ? Wk : z == 2 ? Wv : Wo;
    unsigned short* Wt = z == 0 ? Wqt : z == 1 ? Wkt : z == 2 ? Wvt : Wot;
    const int KW = (z == 3) ? DM_ : WD_;
    const int k0 = (blockIdx.x >> 5) * 32;
    if (k0 >= KW) return;
    const int n0 = (blockIdx.x & 31) * 32;
    const int tx = threadIdx.x & 31, ty = threadIdx.x >> 5;
    for (int dy = ty; dy < 32; dy += 8)
      tt[dy][tx] = W[(size_t)(k0 + dy) * DM_ + n0 + tx];
    __syncthreads();
    for (int dy = ty; dy < 32; dy += 8)
      Wt[(size_t)(n0 + dy) * KW + k0 + tx] = f2bf(tt[tx][dy]);
  }
}

// ---------------- GEMM: C = A[M,KD] @ Bt[N,KD]^T (+bias). 128x128, BK=64 ----------------
// Single-buffered 32KB LDS, launch_bounds(256,3).
// MODE 0 (KD=768), z: 0 -> Qb bf16 [M][DM], 1 -> Kb bf16 [M][DM],
//                     2 -> role-swapped V: A=Wvt (rows R=h*64+dk), Bt=vb -> Vt [B,H,DK,S]
// MODE 2 (KD=1024): A = Xh head-blocked [B,H,S,DK]; fp32 out [M][DM] + bias (nt stores)
template <int MODE, int KD>
__global__ __launch_bounds__(256, 3) void k_mm(
    const unsigned short* __restrict__ A0, const unsigned short* __restrict__ A1,
    const unsigned short* __restrict__ A2, const unsigned short* __restrict__ B0,
    const unsigned short* __restrict__ B1, const unsigned short* __restrict__ B2,
    const float* __restrict__ bias0, const float* __restrict__ bias1,
    const float* __restrict__ bias2, unsigned short* __restrict__ O0,
    unsigned short* __restrict__ O1, unsigned short* __restrict__ O2,
    float* __restrict__ Of) {
  const int z = blockIdx.z;
  const unsigned short* A = z == 0 ? A0 : z == 1 ? A1 : A2;
  const unsigned short* Bt = z == 0 ? B0 : z == 1 ? B1 : B2;
  const float* bias = z == 0 ? bias0 : z == 1 ? bias1 : bias2;

  const int nbn = (MODE == 0 && z == 2) ? 64 : 8;
  const int swz = xcd_swz(blockIdx.x, 512);
  const int m0 = (swz / nbn) * 128, n0 = (swz % nbn) * 128;

  __shared__ unsigned short As[8192];  // 16 KB
  __shared__ unsigned short Bs[8192];  // 16 KB

  const int t = threadIdx.x;
  const int lane = t & 63, w = t >> 6;
  const int l16 = lane & 15, lhi = lane >> 4;
  const int wm = (w >> 1) * 64, wn = (w & 1) * 64;

  f32x4 acc[4][4] = {};

  const int rs0 = t >> 3;              // base dest row (8w..8w+7)
  const int cb0 = (t & 7) << 4;        // colbyte before swizzle

  for (int k0 = 0; k0 < KD; k0 += 64) {
#pragma unroll
    for (int i = 0; i < 4; ++i) {
      const int r = rs0 + i * 32;
      const int cb = cb0 ^ ((r & 7) << 4);  // pre-swizzled global source
      const unsigned short* Ag;
      if (MODE == 2) {
        // Xh [B,H,S,DK]: m=m0+r -> (b, s), k -> (h=k0/64, d)
        Ag = A + ((size_t)((m0 >> 10) * 16 + (k0 >> 6)) * 1024 + (m0 & 1023) + r) * 64 +
             (cb >> 1);
      } else {
        Ag = A + (size_t)(m0 + r) * KD + k0 + (cb >> 1);
      }
      GLOAD_LDS16(Ag, As + w * 512 + i * 2048);
      GLOAD_LDS16(Bt + (size_t)(n0 + r) * KD + k0 + (cb >> 1),
                  Bs + w * 512 + i * 2048);
    }
    __syncthreads();
#pragma unroll
    for (int ksub = 0; ksub < 2; ++ksub) {
      bf16x8 aF[4], bF[4];
#pragma unroll
      for (int i = 0; i < 4; ++i)
        aF[i] = lds_frag(As, wm + i * 16 + l16, ksub * 64 + lhi * 16);
#pragma unroll
      for (int j = 0; j < 4; ++j)
        bF[j] = lds_frag(Bs, wn + j * 16 + l16, ksub * 64 + lhi * 16);
#pragma unroll
      for (int i = 0; i < 4; ++i)
#pragma unroll
        for (int j = 0; j < 4; ++j)
          acc[i][j] = mfma16(bF[j], aF[i], acc[i][j]);
    }
    __syncthreads();
  }

  // ---- direct epilogues ----
#pragma unroll
  for (int i = 0; i < 4; ++i) {
#pragma unroll
    for (int j = 0; j < 4; ++j) {
      if (MODE == 2) {
        int m = m0 + wm + i * 16 + l16;
        int nb = n0 + wn + j * 16 + lhi * 4;
        float4 bb = *reinterpret_cast<const float4*>(&bias[nb]);
        f32x4 o;
        o[0] = acc[i][j][0] + bb.x;
        o[1] = acc[i][j][1] + bb.y;
        o[2] = acc[i][j][2] + bb.z;
        o[3] = acc[i][j][3] + bb.w;
        nt_store_f4(&Of[(size_t)m * DM_ + nb], o);
      } else if (z < 2) {
        int m = m0 + wm + i * 16 + l16;
        int nb = n0 + wn + j * 16 + lhi * 4;
        float4 bb = *reinterpret_cast<const float4*>(&bias[nb]);
        ushort4 o;
        o.x = f2bf(acc[i][j][0] + bb.x);
        o.y = f2bf(acc[i][j][1] + bb.y);
        o.z = f2bf(acc[i][j][2] + bb.z);
        o.w = f2bf(acc[i][j][3] + bb.w);
        unsigned short* Ob = z ? O1 : O0;
        *reinterpret_cast<ushort4*>(&Ob[(size_t)m * DM_ + nb]) = o;
      } else {
        // V role-swap: rows R (= h*64+dk) from A=Wvt, cols = activation row b*S+s
        int R = m0 + wm + i * 16 + l16;
        int Ms = n0 + wn + j * 16 + lhi * 4;
        int b = Ms >> 10, s = Ms & (S_ - 1);
        float bn = bias[R];
        ushort4 o;
        o.x = f2bf(acc[i][j][0] + bn);
        o.y = f2bf(acc[i][j][1] + bn);
        o.z = f2bf(acc[i][j][2] + bn);
        o.w = f2bf(acc[i][j][3] + bn);
        *reinterpret_cast<ushort4*>(
            &O2[((size_t)(b * 1024 + R)) * (size_t)S_ + s]) = o;
      }
    }
  }
}

// ---------------- fused attention (R11 + setprio around PV MFMAs) ----------------
// grid (32,128) -> 4096 blocks, XCD-swizzled. Swapped mfma(K,Q). No max-pass.
// After Plds barrier: waves 0-3 = PV + direct X stores; waves 4-7 = NT P stores.
__global__ __launch_bounds__(512, 4) void k_attn(
    const unsigned short* __restrict__ Qb, const unsigned short* __restrict__ Kb,
    const unsigned short* __restrict__ Vt, float* __restrict__ P,
    unsigned short* __restrict__ Xh) {
  __shared__ unsigned short Plds[32][1032];
  __shared__ float red[32][8];
  __shared__ float rowS[32];
  const int t = threadIdx.x;
  const int lane = t & 63, wid = t >> 6;
  const int l16 = lane & 15, lhi = lane >> 4;

  const int swz = xcd_swz(blockIdx.y * gridDim.x + blockIdx.x,
                          gridDim.x * gridDim.y);
  const int bh = swz >> 5;
  const int q0 = (swz & 31) * 32;
  const int b = bh >> 4, h = bh & 15;
  const unsigned short* Qbase = Qb + ((size_t)(b * S_ + q0) * DM_ + h * DK_);
  const unsigned short* Kbase = Kb + ((size_t)(b * S_) * DM_ + h * DK_);

  // acc[i][j][r] = S[q = i*16+l16][k = n0+j*16+lhi*4+r]
  f32x4 acc[2][8] = {};
  const int n0 = wid * 128;
#pragma unroll
  for (int ks = 0; ks < 2; ++ks) {
    bf16x8 qf[2];
#pragma unroll
    for (int i = 0; i < 2; ++i)
      qf[i] = ld_bf8(Qbase + (size_t)(i * 16 + l16) * DM_ + ks * 32 + lhi * 8);
#pragma unroll
    for (int j = 0; j < 8; ++j) {
      bf16x8 kf = ld_bf8(Kbase + (size_t)(n0 + j * 16 + l16) * DM_ + ks * 32 + lhi * 8);
#pragma unroll
      for (int i = 0; i < 2; ++i)
        acc[i][j] = mfma16(kf, qf[i], acc[i][j]);
    }
  }

  // exp(s/8) + in-lane sum + 2-shuffle reduce + cross-wave sum
#pragma unroll
  for (int i = 0; i < 2; ++i) {
    float s = 0.f;
#pragma unroll
    for (int j = 0; j < 8; ++j)
#pragma unroll
      for (int r = 0; r < 4; ++r) {
        float e = __expf(acc[i][j][r] * 0.125f);
        acc[i][j][r] = e;
        s += e;
      }
    s += __shfl_xor(s, 16);
    s += __shfl_xor(s, 32);
    if (lane < 16) red[i * 16 + l16][wid] = s;
  }
  __syncthreads();
  if (t < 32) {
    float s = red[t][0];
#pragma unroll
    for (int w = 1; w < 8; ++w) s += red[t][w];
    rowS[t] = s;
  }
  __syncthreads();

  // normalize -> Plds (bf16)
#pragma unroll
  for (int i = 0; i < 2; ++i) {
    float inv = 1.f / rowS[i * 16 + l16];
#pragma unroll
    for (int j = 0; j < 8; ++j) {
      f32x4 v = acc[i][j] * inv;
      ushort4 pb;
      pb.x = f2bf(v[0]); pb.y = f2bf(v[1]);
      pb.z = f2bf(v[2]); pb.w = f2bf(v[3]);
      *reinterpret_cast<ushort4*>(&Plds[i * 16 + l16][n0 + j * 16 + lhi * 4]) = pb;
    }
  }
  __syncthreads();

  if (wid < 4) {
    // PV waves: d-block j2 = wid; both row-halves; V loaded once per k-step.
    const int j2 = wid;
    const unsigned short* Vrow = Vt + ((size_t)bh * DK_ + j2 * 16 + l16) * S_;
    f32x4 pacc[2][2] = {};
    __builtin_amdgcn_s_setprio(1);
#pragma unroll 4
    for (int k0 = 0; k0 < S_; k0 += 64) {
      bf16x8 v0 = ld_bf8(Vrow + k0 + lhi * 8);
      bf16x8 v1 = ld_bf8(Vrow + k0 + 32 + lhi * 8);
#pragma unroll
      for (int i2 = 0; i2 < 2; ++i2) {
        bf16x8 a0 = ld_bf8(&Plds[i2 * 16 + l16][k0 + lhi * 8]);
        bf16x8 a1 = ld_bf8(&Plds[i2 * 16 + l16][k0 + 32 + lhi * 8]);
        pacc[i2][0] = mfma16(a0, v0, pacc[i2][0]);
        pacc[i2][1] = mfma16(a1, v1, pacc[i2][1]);
      }
    }
    __builtin_amdgcn_s_setprio(0);
    // direct X stores: 32B-contiguous chunks per instr
#pragma unroll
    for (int i2 = 0; i2 < 2; ++i2) {
      f32x4 x = pacc[i2][0] + pacc[i2][1];
#pragma unroll
      for (int r = 0; r < 4; ++r) {
        int s = q0 + i2 * 16 + lhi * 4 + r;
        Xh[((size_t)(b * H_ + h) * S_ + s) * DK_ + j2 * 16 + l16] = f2bf(x[r]);
      }
    }
  } else {
    // P-store waves: rows (wid-4)*8 .. +7; contiguous 1KB NT stores
    float* Prow0 = P + ((size_t)bh * S_ + q0) * S_;
    const int qbase = (wid - 4) * 8;
#pragma unroll
    for (int rr = 0; rr < 8; ++rr) {
      int q = qbase + rr;
#pragma unroll
      for (int c = 0; c < 4; ++c) {
        ushort4 pv = *reinterpret_cast<const ushort4*>(&Plds[q][c * 256 + lane * 4]);
        f32x4 o;
        o[0] = bf2f(pv.x); o[1] = bf2f(pv.y);
        o[2] = bf2f(pv.z); o[3] = bf2f(pv.w);
        nt_store_f4(&Prow0[(size_t)q * S_ + c * 256 + lane * 4], o);
      }
    }
  }
  // no trailing barrier: Plds not reused; stores drain during retire.
}

// ---------------- launch ----------------

extern "C" void kernel_launch(void* const* d_in, const int* in_sizes, int n_in,
                              void* d_out, int out_size, void* d_ws, size_t ws_size,
                              hipStream_t stream) {
  const float* query = (const float*)d_in[0];
  const float* key   = (const float*)d_in[1];
  const float* value = (const float*)d_in[2];
  const float* Wq = (const float*)d_in[3];
  const float* bq = (const float*)d_in[4];
  const float* Wk = (const float*)d_in[5];
  const float* bk = (const float*)d_in[6];
  const float* Wv = (const float*)d_in[7];
  const float* bv = (const float*)d_in[8];
  const float* Wo = (const float*)d_in[9];
  const float* bo = (const float*)d_in[10];

  char* ws = (char*)d_ws;
  size_t off = 0;
  auto alloc = [&](size_t bytes) {
    void* p = ws + off;
    off += (bytes + 255) & ~(size_t)255;
    return p;
  };
  unsigned short* qb  = (unsigned short*)alloc((size_t)B_ * S_ * WD_ * 2);
  unsigned short* kb  = (unsigned short*)alloc((size_t)B_ * S_ * WD_ * 2);
  unsigned short* vb  = (unsigned short*)alloc((size_t)B_ * S_ * WD_ * 2);
  unsigned short* Wqt = (unsigned short*)alloc((size_t)DM_ * WD_ * 2);
  unsigned short* Wkt = (unsigned short*)alloc((size_t)DM_ * WD_ * 2);
  unsigned short* Wvt = (unsigned short*)alloc((size_t)DM_ * WD_ * 2);
  unsigned short* Wot = (unsigned short*)alloc((size_t)DM_ * DM_ * 2);
  unsigned short* Qb  = (unsigned short*)alloc((size_t)B_ * S_ * DM_ * 2);
  unsigned short* Kb  = (unsigned short*)alloc((size_t)B_ * S_ * DM_ * 2);
  unsigned short* Vt  = (unsigned short*)alloc((size_t)B_ * H_ * DK_ * S_ * 2);
  unsigned short* Xh  = (unsigned short*)alloc((size_t)B_ * H_ * S_ * DK_ * 2);

  float* out = (float*)d_out;
  float* P = out + (size_t)B_ * S_ * DM_;  // p_attn region

  const int nAct = B_ * S_ * WD_;
  k_prep<<<dim3(1024, 7), 256, 0, stream>>>(
      query, key, value, Wq, Wk, Wv, Wo, qb, kb, vb, Wqt, Wkt, Wvt, Wot, nAct);

  // QKV in one launch: z0=Q (A=qb,B=Wqt), z1=K (A=kb,B=Wkt), z2=V role-swap (A=Wvt,B=vb)
  k_mm<0, WD_><<<dim3(512, 1, 3), 256, 0, stream>>>(
      qb, kb, Wvt, Wqt, Wkt, vb, bq, bk, bv, Qb, Kb, Vt, nullptr);

  k_attn<<<dim3(32, 128), 512, 0, stream>>>(Qb, Kb, Vt, P, Xh);

  k_mm<2, DM_><<<dim3(512, 1, 1), 256, 0, stream>>>(
      Xh, nullptr, nullptr, Wot, nullptr, nullptr, bo, nullptr, nullptr,
      nullptr, nullptr, nullptr, out);
}

// Round 15
// 275.689 us; speedup vs baseline: 1.0431x; 1.0431x over previous
//
#include <hip/hip_runtime.h>
#include <hip/hip_bf16.h>
#include <cstdint>
#include <cstddef>

// MHA forward: out = (softmax(QK^T/8) V) Wo + bo, plus p_attn (fp32).
// R15 = exact revert to R11 (best measured: 275.8us).
// Wins baked in: contiguous NT P-stores (dead-stream L2 bypass), wave-specialized
// attn tail (PV || P-drain), XCD swizzle, swapped QK^T, no-max softmax,
// 128^2 single-buffer GEMMs @ 3 blocks/CU with swizzled LDS + global_load_lds.

#define H_ 16
#define DK_ 64
#define DM_ 1024
#define WD_ 768
#define B_ 8
#define S_ 1024

typedef float f32x4 __attribute__((ext_vector_type(4)));
typedef __bf16 bf16x8 __attribute__((ext_vector_type(8)));
typedef short s16x8 __attribute__((ext_vector_type(8)));

__device__ __forceinline__ unsigned short f2bf(float x) {
  unsigned int u = __builtin_bit_cast(unsigned int, x);
  u += 0x7FFFu + ((u >> 16) & 1u);  // RNE
  return (unsigned short)(u >> 16);
}

__device__ __forceinline__ float bf2f(unsigned short b) {
  return __builtin_bit_cast(float, (unsigned int)b << 16);
}

__device__ __forceinline__ f32x4 mfma16(bf16x8 a, bf16x8 b, f32x4 c) {
  return __builtin_amdgcn_mfma_f32_16x16x32_bf16(a, b, c, 0, 0, 0);
}

__device__ __forceinline__ bf16x8 ld_bf8(const unsigned short* p) {
  return *reinterpret_cast<const bf16x8*>(p);
}

__device__ __forceinline__ void nt_store_f4(float* p, f32x4 v) {
  __builtin_nontemporal_store(v, reinterpret_cast<f32x4*>(p));
}

// bijective XCD swizzle (count % 8 == 0)
__device__ __forceinline__ int xcd_swz(int wg, int n) {
  int q = n >> 3;
  return (wg & 7) * q + (wg >> 3);
}

#define GLOAD_LDS16(g, l)                                            \
  __builtin_amdgcn_global_load_lds(                                  \
      (const __attribute__((address_space(1))) void*)(g),            \
      (__attribute__((address_space(3))) void*)(l), 16, 0, 0)

// swizzled LDS fragment read: row stride 128B, cb ^= (row&7)<<4
__device__ __forceinline__ bf16x8 lds_frag(const unsigned short* base, int row, int cb) {
  return *reinterpret_cast<const bf16x8*>(
      reinterpret_cast<const char*>(base) + row * 128 + (cb ^ ((row & 7) << 4)));
}

// ---------------- fp32 -> bf16 conversion (y selects tensor) ----------------
__global__ void k_conv3(const float* __restrict__ q, const float* __restrict__ k,
                        const float* __restrict__ v, unsigned short* __restrict__ qo,
                        unsigned short* __restrict__ ko, unsigned short* __restrict__ vo,
                        int n) {
  const float* in = blockIdx.y == 0 ? q : blockIdx.y == 1 ? k : v;
  unsigned short* out = blockIdx.y == 0 ? qo : blockIdx.y == 1 ? ko : vo;
  int i0 = (blockIdx.x * blockDim.x + threadIdx.x) * 8;
  int stride = gridDim.x * blockDim.x * 8;
  for (int i = i0; i < n; i += stride) {
    float4 a = *reinterpret_cast<const float4*>(in + i);
    float4 b = *reinterpret_cast<const float4*>(in + i + 4);
    s16x8 o;
    o[0] = (short)f2bf(a.x); o[1] = (short)f2bf(a.y);
    o[2] = (short)f2bf(a.z); o[3] = (short)f2bf(a.w);
    o[4] = (short)f2bf(b.x); o[5] = (short)f2bf(b.y);
    o[6] = (short)f2bf(b.z); o[7] = (short)f2bf(b.w);
    *reinterpret_cast<s16x8*>(out + i) = o;
  }
}

// ---------------- weight transpose+convert, all 4 weights, z selects ----------------
__global__ void k_tconvA(const float* __restrict__ Wq, const float* __restrict__ Wk,
                         const float* __restrict__ Wv, const float* __restrict__ Wo,
                         unsigned short* __restrict__ Wqt, unsigned short* __restrict__ Wkt,
                         unsigned short* __restrict__ Wvt, unsigned short* __restrict__ Wot) {
  __shared__ float tt[32][33];
  const int z = blockIdx.z;
  const float* W = z == 0 ? Wq : z == 1 ? Wk : z == 2 ? Wv : Wo;
  unsigned short* Wt = z == 0 ? Wqt : z == 1 ? Wkt : z == 2 ? Wvt : Wot;
  const int KW = (z == 3) ? DM_ : WD_;
  const int k0 = blockIdx.y * 32;
  if (k0 >= KW) return;
  const int n0 = blockIdx.x * 32;
  int tx = threadIdx.x, ty = threadIdx.y;
  for (int dy = ty; dy < 32; dy += 8)
    tt[dy][tx] = W[(size_t)(k0 + dy) * DM_ + n0 + tx];
  __syncthreads();
  for (int dy = ty; dy < 32; dy += 8)
    Wt[(size_t)(n0 + dy) * KW + k0 + tx] = f2bf(tt[tx][dy]);
}

// ---------------- GEMM: C = A[M,KD] @ Bt[N,KD]^T (+bias). 128x128, BK=64 ----------------
// Single-buffered 32KB LDS, launch_bounds(256,3) -> ~3 blocks/CU.
// MODE 0 (KD=768), z: 0 -> Qb bf16 [M][DM], 1 -> Kb bf16 [M][DM],
//                     2 -> role-swapped V: A=Wvt (rows R=h*64+dk), Bt=vb -> Vt [B,H,DK,S]
// MODE 2 (KD=1024): A = Xh head-blocked [B,H,S,DK]; fp32 out [M][DM] + bias (nt stores)
template <int MODE, int KD>
__global__ __launch_bounds__(256, 3) void k_mm(
    const unsigned short* __restrict__ A0, const unsigned short* __restrict__ A1,
    const unsigned short* __restrict__ A2, const unsigned short* __restrict__ B0,
    const unsigned short* __restrict__ B1, const unsigned short* __restrict__ B2,
    const float* __restrict__ bias0, const float* __restrict__ bias1,
    const float* __restrict__ bias2, unsigned short* __restrict__ O0,
    unsigned short* __restrict__ O1, unsigned short* __restrict__ O2,
    float* __restrict__ Of) {
  const int z = blockIdx.z;
  const unsigned short* A = z == 0 ? A0 : z == 1 ? A1 : A2;
  const unsigned short* Bt = z == 0 ? B0 : z == 1 ? B1 : B2;
  const float* bias = z == 0 ? bias0 : z == 1 ? bias1 : bias2;

  const int nbn = (MODE == 0 && z == 2) ? 64 : 8;
  const int swz = xcd_swz(blockIdx.x, 512);
  const int m0 = (swz / nbn) * 128, n0 = (swz % nbn) * 128;

  __shared__ unsigned short As[8192];  // 16 KB
  __shared__ unsigned short Bs[8192];  // 16 KB

  const int t = threadIdx.x;
  const int lane = t & 63, w = t >> 6;
  const int l16 = lane & 15, lhi = lane >> 4;
  const int wm = (w >> 1) * 64, wn = (w & 1) * 64;

  f32x4 acc[4][4] = {};

  const int rs0 = t >> 3;              // base dest row (8w..8w+7)
  const int cb0 = (t & 7) << 4;        // colbyte before swizzle

  for (int k0 = 0; k0 < KD; k0 += 64) {
#pragma unroll
    for (int i = 0; i < 4; ++i) {
      const int r = rs0 + i * 32;
      const int cb = cb0 ^ ((r & 7) << 4);  // pre-swizzled global source
      const unsigned short* Ag;
      if (MODE == 2) {
        // Xh [B,H,S,DK]: m=m0+r -> (b, s), k -> (h=k0/64, d)
        Ag = A + ((size_t)((m0 >> 10) * 16 + (k0 >> 6)) * 1024 + (m0 & 1023) + r) * 64 +
             (cb >> 1);
      } else {
        Ag = A + (size_t)(m0 + r) * KD + k0 + (cb >> 1);
      }
      GLOAD_LDS16(Ag, As + w * 512 + i * 2048);
      GLOAD_LDS16(Bt + (size_t)(n0 + r) * KD + k0 + (cb >> 1),
                  Bs + w * 512 + i * 2048);
    }
    __syncthreads();
#pragma unroll
    for (int ksub = 0; ksub < 2; ++ksub) {
      bf16x8 aF[4], bF[4];
#pragma unroll
      for (int i = 0; i < 4; ++i)
        aF[i] = lds_frag(As, wm + i * 16 + l16, ksub * 64 + lhi * 16);
#pragma unroll
      for (int j = 0; j < 4; ++j)
        bF[j] = lds_frag(Bs, wn + j * 16 + l16, ksub * 64 + lhi * 16);
#pragma unroll
      for (int i = 0; i < 4; ++i)
#pragma unroll
        for (int j = 0; j < 4; ++j)
          acc[i][j] = mfma16(bF[j], aF[i], acc[i][j]);
    }
    __syncthreads();
  }

  // ---- direct epilogues ----
#pragma unroll
  for (int i = 0; i < 4; ++i) {
#pragma unroll
    for (int j = 0; j < 4; ++j) {
      if (MODE == 2) {
        int m = m0 + wm + i * 16 + l16;
        int nb = n0 + wn + j * 16 + lhi * 4;
        float4 bb = *reinterpret_cast<const float4*>(&bias[nb]);
        f32x4 o;
        o[0] = acc[i][j][0] + bb.x;
        o[1] = acc[i][j][1] + bb.y;
        o[2] = acc[i][j][2] + bb.z;
        o[3] = acc[i][j][3] + bb.w;
        nt_store_f4(&Of[(size_t)m * DM_ + nb], o);
      } else if (z < 2) {
        int m = m0 + wm + i * 16 + l16;
        int nb = n0 + wn + j * 16 + lhi * 4;
        float4 bb = *reinterpret_cast<const float4*>(&bias[nb]);
        ushort4 o;
        o.x = f2bf(acc[i][j][0] + bb.x);
        o.y = f2bf(acc[i][j][1] + bb.y);
        o.z = f2bf(acc[i][j][2] + bb.z);
        o.w = f2bf(acc[i][j][3] + bb.w);
        unsigned short* Ob = z ? O1 : O0;
        *reinterpret_cast<ushort4*>(&Ob[(size_t)m * DM_ + nb]) = o;
      } else {
        // V role-swap: rows R (= h*64+dk) from A=Wvt, cols = activation row b*S+s
        int R = m0 + wm + i * 16 + l16;
        int Ms = n0 + wn + j * 16 + lhi * 4;
        int b = Ms >> 10, s = Ms & (S_ - 1);
        float bn = bias[R];
        ushort4 o;
        o.x = f2bf(acc[i][j][0] + bn);
        o.y = f2bf(acc[i][j][1] + bn);
        o.z = f2bf(acc[i][j][2] + bn);
        o.w = f2bf(acc[i][j][3] + bn);
        *reinterpret_cast<ushort4*>(
            &O2[((size_t)(b * 1024 + R)) * (size_t)S_ + s]) = o;
      }
    }
  }
}

// ---------------- fused attention (wave-specialized tail) ----------------
// grid (32,128) -> 4096 blocks, XCD-swizzled. Swapped mfma(K,Q). No max-pass.
// After Plds barrier: waves 0-3 = PV + direct X stores; waves 4-7 = NT P stores.
// No trailing barrier: store drain overlaps PV compute / next block warm-up.
__global__ __launch_bounds__(512, 4) void k_attn(
    const unsigned short* __restrict__ Qb, const unsigned short* __restrict__ Kb,
    const unsigned short* __restrict__ Vt, float* __restrict__ P,
    unsigned short* __restrict__ Xh) {
  __shared__ unsigned short Plds[32][1032];
  __shared__ float red[32][8];
  __shared__ float rowS[32];
  const int t = threadIdx.x;
  const int lane = t & 63, wid = t >> 6;
  const int l16 = lane & 15, lhi = lane >> 4;

  const int swz = xcd_swz(blockIdx.y * gridDim.x + blockIdx.x,
                          gridDim.x * gridDim.y);
  const int bh = swz >> 5;
  const int q0 = (swz & 31) * 32;
  const int b = bh >> 4, h = bh & 15;
  const unsigned short* Qbase = Qb + ((size_t)(b * S_ + q0) * DM_ + h * DK_);
  const unsigned short* Kbase = Kb + ((size_t)(b * S_) * DM_ + h * DK_);

  // acc[i][j][r] = S[q = i*16+l16][k = n0+j*16+lhi*4+r]
  f32x4 acc[2][8] = {};
  const int n0 = wid * 128;
#pragma unroll
  for (int ks = 0; ks < 2; ++ks) {
    bf16x8 qf[2];
#pragma unroll
    for (int i = 0; i < 2; ++i)
      qf[i] = ld_bf8(Qbase + (size_t)(i * 16 + l16) * DM_ + ks * 32 + lhi * 8);
#pragma unroll
    for (int j = 0; j < 8; ++j) {
      bf16x8 kf = ld_bf8(Kbase + (size_t)(n0 + j * 16 + l16) * DM_ + ks * 32 + lhi * 8);
#pragma unroll
      for (int i = 0; i < 2; ++i)
        acc[i][j] = mfma16(kf, qf[i], acc[i][j]);
    }
  }

  // exp(s/8) + in-lane sum + 2-shuffle reduce + cross-wave sum
#pragma unroll
  for (int i = 0; i < 2; ++i) {
    float s = 0.f;
#pragma unroll
    for (int j = 0; j < 8; ++j)
#pragma unroll
      for (int r = 0; r < 4; ++r) {
        float e = __expf(acc[i][j][r] * 0.125f);
        acc[i][j][r] = e;
        s += e;
      }
    s += __shfl_xor(s, 16);
    s += __shfl_xor(s, 32);
    if (lane < 16) red[i * 16 + l16][wid] = s;
  }
  __syncthreads();
  if (t < 32) {
    float s = red[t][0];
#pragma unroll
    for (int w = 1; w < 8; ++w) s += red[t][w];
    rowS[t] = s;
  }
  __syncthreads();

  // normalize -> Plds (bf16)
#pragma unroll
  for (int i = 0; i < 2; ++i) {
    float inv = 1.f / rowS[i * 16 + l16];
#pragma unroll
    for (int j = 0; j < 8; ++j) {
      f32x4 v = acc[i][j] * inv;
      ushort4 pb;
      pb.x = f2bf(v[0]); pb.y = f2bf(v[1]);
      pb.z = f2bf(v[2]); pb.w = f2bf(v[3]);
      *reinterpret_cast<ushort4*>(&Plds[i * 16 + l16][n0 + j * 16 + lhi * 4]) = pb;
    }
  }
  __syncthreads();

  if (wid < 4) {
    // PV waves: d-block j2 = wid; both row-halves; V loaded once per k-step.
    const int j2 = wid;
    const unsigned short* Vrow = Vt + ((size_t)bh * DK_ + j2 * 16 + l16) * S_;
    f32x4 pacc[2][2] = {};
#pragma unroll 4
    for (int k0 = 0; k0 < S_; k0 += 64) {
      bf16x8 v0 = ld_bf8(Vrow + k0 + lhi * 8);
      bf16x8 v1 = ld_bf8(Vrow + k0 + 32 + lhi * 8);
#pragma unroll
      for (int i2 = 0; i2 < 2; ++i2) {
        bf16x8 a0 = ld_bf8(&Plds[i2 * 16 + l16][k0 + lhi * 8]);
        bf16x8 a1 = ld_bf8(&Plds[i2 * 16 + l16][k0 + 32 + lhi * 8]);
        pacc[i2][0] = mfma16(a0, v0, pacc[i2][0]);
        pacc[i2][1] = mfma16(a1, v1, pacc[i2][1]);
      }
    }
    // direct X stores: 32B-contiguous chunks per instr (2x amp on tiny X: ok)
#pragma unroll
    for (int i2 = 0; i2 < 2; ++i2) {
      f32x4 x = pacc[i2][0] + pacc[i2][1];
#pragma unroll
      for (int r = 0; r < 4; ++r) {
        int s = q0 + i2 * 16 + lhi * 4 + r;
        Xh[((size_t)(b * H_ + h) * S_ + s) * DK_ + j2 * 16 + l16] = f2bf(x[r]);
      }
    }
  } else {
    // P-store waves: rows (wid-4)*8 .. +7; contiguous 1KB NT stores
    float* Prow0 = P + ((size_t)bh * S_ + q0) * S_;
    const int qbase = (wid - 4) * 8;
#pragma unroll
    for (int rr = 0; rr < 8; ++rr) {
      int q = qbase + rr;
#pragma unroll
      for (int c = 0; c < 4; ++c) {
        ushort4 pv = *reinterpret_cast<const ushort4*>(&Plds[q][c * 256 + lane * 4]);
        f32x4 o;
        o[0] = bf2f(pv.x); o[1] = bf2f(pv.y);
        o[2] = bf2f(pv.z); o[3] = bf2f(pv.w);
        nt_store_f4(&Prow0[(size_t)q * S_ + c * 256 + lane * 4], o);
      }
    }
  }
  // no trailing barrier: Plds not reused; stores drain during retire.
}

// ---------------- launch ----------------

extern "C" void kernel_launch(void* const* d_in, const int* in_sizes, int n_in,
                              void* d_out, int out_size, void* d_ws, size_t ws_size,
                              hipStream_t stream) {
  const float* query = (const float*)d_in[0];
  const float* key   = (const float*)d_in[1];
  const float* value = (const float*)d_in[2];
  const float* Wq = (const float*)d_in[3];
  const float* bq = (const float*)d_in[4];
  const float* Wk = (const float*)d_in[5];
  const float* bk = (const float*)d_in[6];
  const float* Wv = (const float*)d_in[7];
  const float* bv = (const float*)d_in[8];
  const float* Wo = (const float*)d_in[9];
  const float* bo = (const float*)d_in[10];

  char* ws = (char*)d_ws;
  size_t off = 0;
  auto alloc = [&](size_t bytes) {
    void* p = ws + off;
    off += (bytes + 255) & ~(size_t)255;
    return p;
  };
  unsigned short* qb  = (unsigned short*)alloc((size_t)B_ * S_ * WD_ * 2);
  unsigned short* kb  = (unsigned short*)alloc((size_t)B_ * S_ * WD_ * 2);
  unsigned short* vb  = (unsigned short*)alloc((size_t)B_ * S_ * WD_ * 2);
  unsigned short* Wqt = (unsigned short*)alloc((size_t)DM_ * WD_ * 2);
  unsigned short* Wkt = (unsigned short*)alloc((size_t)DM_ * WD_ * 2);
  unsigned short* Wvt = (unsigned short*)alloc((size_t)DM_ * WD_ * 2);
  unsigned short* Wot = (unsigned short*)alloc((size_t)DM_ * DM_ * 2);
  unsigned short* Qb  = (unsigned short*)alloc((size_t)B_ * S_ * DM_ * 2);
  unsigned short* Kb  = (unsigned short*)alloc((size_t)B_ * S_ * DM_ * 2);
  unsigned short* Vt  = (unsigned short*)alloc((size_t)B_ * H_ * DK_ * S_ * 2);
  unsigned short* Xh  = (unsigned short*)alloc((size_t)B_ * H_ * S_ * DK_ * 2);

  float* out = (float*)d_out;
  float* P = out + (size_t)B_ * S_ * DM_;  // p_attn region

  const int nAct = B_ * S_ * WD_;
  k_conv3<<<dim3(1024, 3), 256, 0, stream>>>(query, key, value, qb, kb, vb, nAct);
  k_tconvA<<<dim3(32, 32, 4), dim3(32, 8), 0, stream>>>(
      Wq, Wk, Wv, Wo, Wqt, Wkt, Wvt, Wot);

  // QKV in one launch: z0=Q (A=qb,B=Wqt), z1=K (A=kb,B=Wkt), z2=V role-swap (A=Wvt,B=vb)
  k_mm<0, WD_><<<dim3(512, 1, 3), 256, 0, stream>>>(
      qb, kb, Wvt, Wqt, Wkt, vb, bq, bk, bv, Qb, Kb, Vt, nullptr);

  k_attn<<<dim3(32, 128), 512, 0, stream>>>(Qb, Kb, Vt, P, Xh);

  k_mm<2, DM_><<<dim3(512, 1, 1), 256, 0, stream>>>(
      Xh, nullptr, nullptr, Wot, nullptr, nullptr, bo, nullptr, nullptr,
      nullptr, nullptr, nullptr, out);
}